// Round 4
// baseline (392.775 us; speedup 1.0000x reference)
//
#include <hip/hip_runtime.h>

#define NUM_USERS  150000
#define NUM_ITEMS  140000
#define NUM_BRANDS 10000
#define N_NODES    300000
#define DIM        64
#define N_EDGES    1200000
#define OUT_ROWS   290000          // users + items

#define CHUNK      1024            // elements per scan block
#define NB         ((N_NODES + CHUNK - 1) / CHUNK)   // 293 scan blocks

// ---------------------------------------------------------------------------
// histogram of destination degrees
// ---------------------------------------------------------------------------
__global__ void lgcn_hist(const int* __restrict__ dst, int* __restrict__ counts) {
    int e = blockIdx.x * blockDim.x + threadIdx.x;
    if (e >= N_EDGES) return;
    atomicAdd(&counts[dst[e]], 1);
}

// ---------------------------------------------------------------------------
// scan phase 1: per-1024-chunk exclusive scan (256 thr x 4 elem), chunk sums
// ---------------------------------------------------------------------------
__global__ void lgcn_scan_p1(const int* __restrict__ counts,
                             int* __restrict__ rowptr,
                             int* __restrict__ blockSums) {
    __shared__ int ts[256];
    int b    = blockIdx.x;
    int base = b * CHUNK;
    int t    = threadIdx.x;
    int c[4];
    int s = 0;
#pragma unroll
    for (int i = 0; i < 4; ++i) {
        int g = base + t * 4 + i;
        c[i] = (g < N_NODES) ? counts[g] : 0;
        s += c[i];
    }
    ts[t] = s;
    __syncthreads();
    for (int off = 1; off < 256; off <<= 1) {
        int v = (t >= off) ? ts[t - off] : 0;
        __syncthreads();
        ts[t] += v;
        __syncthreads();
    }
    int run = ts[t] - s;     // exclusive prefix of this thread's 4-group
#pragma unroll
    for (int i = 0; i < 4; ++i) {
        int g = base + t * 4 + i;
        if (g < N_NODES) rowptr[g] = run;
        run += c[i];
    }
    if (t == 255) blockSums[b] = ts[255];
}

// ---------------------------------------------------------------------------
// scan phase 2: single block exclusive-scans the NB (=293) chunk sums
// ---------------------------------------------------------------------------
__global__ void lgcn_scan_p2(int* __restrict__ blockSums) {
    __shared__ int sh[512];
    int t = threadIdx.x;
    int v = (t < NB) ? blockSums[t] : 0;
    sh[t] = v;
    __syncthreads();
    for (int off = 1; off < 512; off <<= 1) {
        int u = (t >= off) ? sh[t - off] : 0;
        __syncthreads();
        sh[t] += u;
        __syncthreads();
    }
    if (t < NB) blockSums[t] = sh[t] - v;   // exclusive
}

// ---------------------------------------------------------------------------
// scan phase 3: add chunk offsets; cursor = rowptr; rowptr[N_NODES] = N_EDGES
// ---------------------------------------------------------------------------
__global__ void lgcn_scan_p3(int* __restrict__ rowptr,
                             const int* __restrict__ blockSums,
                             int* __restrict__ cursor) {
    int b    = blockIdx.x;
    int base = b * CHUNK;
    int t    = threadIdx.x;
    int off  = blockSums[b];
#pragma unroll
    for (int i = 0; i < 4; ++i) {
        int g = base + t * 4 + i;
        if (g < N_NODES) {
            int r = rowptr[g] + off;
            rowptr[g] = r;
            cursor[g] = r;
        }
    }
    if (b == 0 && t == 0) rowptr[N_NODES] = N_EDGES;
}

// ---------------------------------------------------------------------------
// perm scatter: only a 4B edge index goes to the random position.
// Target buffer is 4.8 MB -> L2-resident, write amplification collapses.
// ---------------------------------------------------------------------------
__global__ void lgcn_perm(const int* __restrict__ dst,
                          int* __restrict__ cursor,
                          int* __restrict__ perm) {
    int e = blockIdx.x * blockDim.x + threadIdx.x;
    if (e >= N_EDGES) return;
    int pos = atomicAdd(&cursor[dst[e]], 1);
    perm[pos] = e;
}

// ---------------------------------------------------------------------------
// pack: sequential 8B csr writes (full lines), random 4B reads of src/vals
// ---------------------------------------------------------------------------
__global__ void lgcn_pack(const int*   __restrict__ perm,
                          const int*   __restrict__ src,
                          const float* __restrict__ vals,
                          uint2* __restrict__ csr) {
    int p = blockIdx.x * blockDim.x + threadIdx.x;
    if (p >= N_EDGES) return;
    int e = perm[p];
    uint2 rec;
    rec.x = (unsigned)src[e];
    rec.y = __float_as_uint(vals[e]);
    csr[p] = rec;
}

// ---------------------------------------------------------------------------
// ego row lookup: concat(user,item,brand) without materializing the concat
// ---------------------------------------------------------------------------
__device__ __forceinline__ const float4* ego_row(const float* __restrict__ user,
                                                 const float* __restrict__ item,
                                                 const float* __restrict__ brand,
                                                 int r) {
    if (r < NUM_USERS)
        return reinterpret_cast<const float4*>(user) + (r << 4);
    else if (r < NUM_USERS + NUM_ITEMS)
        return reinterpret_cast<const float4*>(item) + ((r - NUM_USERS) << 4);
    else
        return reinterpret_cast<const float4*>(brand) + ((r - NUM_USERS - NUM_ITEMS) << 4);
}

// ---------------------------------------------------------------------------
// gather SpMM: 16 lanes per dst node (float4 each), 4 nodes per wave.
// 2-deep software pipeline. LAYER=1 reads ego arrays, writes h1.
// LAYER=2 reads h1, writes h2. LAYER=3 reads h2, fuses the full residual:
// out = (ego + h1 + h2 + sum) * 0.25.
// ---------------------------------------------------------------------------
template <int LAYER>
__global__ void lgcn_gather(const int*   __restrict__ rowptr,
                            const uint2* __restrict__ csr,
                            const float* __restrict__ user,
                            const float* __restrict__ item,
                            const float* __restrict__ brand,
                            const float* __restrict__ h1,
                            const float* __restrict__ h2,
                            float*       __restrict__ h_out,
                            float*       __restrict__ out) {
    int t    = blockIdx.x * blockDim.x + threadIdx.x;   // node*16 + q
    int node = t >> 4;
    int q    = t & 15;
    int beg = rowptr[node];
    int end = rowptr[node + 1];
    const float* h_src = (LAYER == 2) ? h1 : h2;        // LAYER 1 ignores this
    float4 sum = make_float4(0.f, 0.f, 0.f, 0.f);
    if (beg < end) {
        uint2 rec0 = csr[beg];
        uint2 rec1 = csr[(beg + 1 < end) ? beg + 1 : beg];
        const float4* p0 = (LAYER == 1)
            ? ego_row(user, item, brand, (int)rec0.x)
            : reinterpret_cast<const float4*>(h_src) + ((int)rec0.x << 4);
        float4 r0 = p0[q];
        for (int j = beg; j < end; ++j) {
            int jn = j + 2 < end ? j + 2 : end - 1;
            uint2 rec2 = csr[jn];                       // prefetch rec, 2 ahead
            const float4* p1 = (LAYER == 1)
                ? ego_row(user, item, brand, (int)rec1.x)
                : reinterpret_cast<const float4*>(h_src) + ((int)rec1.x << 4);
            float4 r1 = p1[q];
            float v = __uint_as_float(rec0.y);
            sum.x = fmaf(r0.x, v, sum.x);
            sum.y = fmaf(r0.y, v, sum.y);
            sum.z = fmaf(r0.z, v, sum.z);
            sum.w = fmaf(r0.w, v, sum.w);
            rec0 = rec1; rec1 = rec2; r0 = r1;
        }
    }
    if (LAYER != 3) {
        *reinterpret_cast<float4*>(h_out + t * 4) = sum;
    } else if (node < OUT_ROWS) {
        float4 eg = ego_row(user, item, brand, node)[q];
        float4 a1 = *(reinterpret_cast<const float4*>(h1) + (node << 4) + q);
        float4 a2 = *(reinterpret_cast<const float4*>(h2) + (node << 4) + q);
        float4 o;
        o.x = (eg.x + a1.x + a2.x + sum.x) * 0.25f;
        o.y = (eg.y + a1.y + a2.y + sum.y) * 0.25f;
        o.z = (eg.z + a1.z + a2.z + sum.z) * 0.25f;
        o.w = (eg.w + a1.w + a2.w + sum.w) * 0.25f;
        *reinterpret_cast<float4*>(out + t * 4) = o;
    }
}

extern "C" void kernel_launch(void* const* d_in, const int* in_sizes, int n_in,
                              void* d_out, int out_size, void* d_ws, size_t ws_size,
                              hipStream_t stream) {
    const float* user  = (const float*)d_in[0];
    const float* item  = (const float*)d_in[1];
    const float* brand = (const float*)d_in[2];
    const float* vals  = (const float*)d_in[3];
    const int*   src   = (const int*)d_in[4];
    const int*   dst   = (const int*)d_in[5];
    float* out = (float*)d_out;

    // workspace layout (32-bit words); keep csr 8B-aligned
    size_t W = 0;
    float* h1 = (float*)d_ws;                  W += (size_t)N_NODES * DIM;
    float* h2 = (float*)d_ws + W;              W += (size_t)N_NODES * DIM;
    uint2* csr = (uint2*)((float*)d_ws + W);   W += (size_t)N_EDGES * 2;
    int* perm      = (int*)((float*)d_ws + W); W += N_EDGES;
    int* rowptr    = (int*)((float*)d_ws + W); W += N_NODES + 2;
    int* counts    = (int*)((float*)d_ws + W); W += N_NODES;
    int* cursor    = (int*)((float*)d_ws + W); W += N_NODES;
    int* blockSums = (int*)((float*)d_ws + W); W += 512;
    (void)ws_size; (void)n_in; (void)in_sizes; (void)out_size;

    const int edgeBlocks   = (N_EDGES + 255) / 256;     // 4688
    const int gatherBlocks = (N_NODES * 16) / 256;      // 18750 (16 thr/node)

    // zero degree counters (poisoned workspace, and hist accumulates)
    hipMemsetAsync(counts, 0, (size_t)N_NODES * sizeof(int), stream);

    // build dst-sorted CSR: hist -> scan -> perm scatter -> sequential pack
    lgcn_hist   <<<edgeBlocks, 256, 0, stream>>>(dst, counts);
    lgcn_scan_p1<<<NB, 256, 0, stream>>>(counts, rowptr, blockSums);
    lgcn_scan_p2<<<1, 512, 0, stream>>>(blockSums);
    lgcn_scan_p3<<<NB, 256, 0, stream>>>(rowptr, blockSums, cursor);
    lgcn_perm   <<<edgeBlocks, 256, 0, stream>>>(dst, cursor, perm);
    lgcn_pack   <<<edgeBlocks, 256, 0, stream>>>(perm, src, vals, csr);

    // 3 atomic-free SpMM layers; residual sum fused into layer 3
    lgcn_gather<1><<<gatherBlocks, 256, 0, stream>>>(rowptr, csr, user, item, brand,
                                                     h1, h2, h1, out);
    lgcn_gather<2><<<gatherBlocks, 256, 0, stream>>>(rowptr, csr, user, item, brand,
                                                     h1, h2, h2, out);
    lgcn_gather<3><<<gatherBlocks, 256, 0, stream>>>(rowptr, csr, user, item, brand,
                                                     h1, h2, nullptr, out);
}

// Round 5
// 330.265 us; speedup vs baseline: 1.1893x; 1.1893x over previous
//
#include <hip/hip_runtime.h>

#define NUM_USERS  150000
#define NUM_ITEMS  140000
#define NUM_BRANDS 10000
#define N_NODES    300000
#define DIM        64
#define N_EDGES    1200000
#define OUT_ROWS   290000          // users + items

#define CHUNK      1024            // elements per scan block
#define NB         ((N_NODES + CHUNK - 1) / CHUNK)   // 293 scan blocks

#define NBIN       8               // one bin per XCD
#define BINSZ      (N_EDGES / NBIN)                  // 150000 csr records

// ---------------------------------------------------------------------------
// histogram of destination degrees + per-edge rank within its row
// ---------------------------------------------------------------------------
__global__ void lgcn_hist(const int* __restrict__ dst,
                          int* __restrict__ counts,
                          int* __restrict__ rank) {
    int e = blockIdx.x * blockDim.x + threadIdx.x;
    if (e >= N_EDGES) return;
    rank[e] = atomicAdd(&counts[dst[e]], 1);
}

// ---------------------------------------------------------------------------
// scan phase 1: per-1024-chunk exclusive scan (256 thr x 4 elem), chunk sums
// ---------------------------------------------------------------------------
__global__ void lgcn_scan_p1(const int* __restrict__ counts,
                             int* __restrict__ rowptr,
                             int* __restrict__ blockSums) {
    __shared__ int ts[256];
    int b    = blockIdx.x;
    int base = b * CHUNK;
    int t    = threadIdx.x;
    int c[4];
    int s = 0;
#pragma unroll
    for (int i = 0; i < 4; ++i) {
        int g = base + t * 4 + i;
        c[i] = (g < N_NODES) ? counts[g] : 0;
        s += c[i];
    }
    ts[t] = s;
    __syncthreads();
    for (int off = 1; off < 256; off <<= 1) {
        int v = (t >= off) ? ts[t - off] : 0;
        __syncthreads();
        ts[t] += v;
        __syncthreads();
    }
    int run = ts[t] - s;     // exclusive prefix of this thread's 4-group
#pragma unroll
    for (int i = 0; i < 4; ++i) {
        int g = base + t * 4 + i;
        if (g < N_NODES) rowptr[g] = run;
        run += c[i];
    }
    if (t == 255) blockSums[b] = ts[255];
}

// ---------------------------------------------------------------------------
// scan phase 2: single block exclusive-scans the NB (=293) chunk sums
// ---------------------------------------------------------------------------
__global__ void lgcn_scan_p2(int* __restrict__ blockSums) {
    __shared__ int sh[512];
    int t = threadIdx.x;
    int v = (t < NB) ? blockSums[t] : 0;
    sh[t] = v;
    __syncthreads();
    for (int off = 1; off < 512; off <<= 1) {
        int u = (t >= off) ? sh[t - off] : 0;
        __syncthreads();
        sh[t] += u;
        __syncthreads();
    }
    if (t < NB) blockSums[t] = sh[t] - v;   // exclusive
}

// ---------------------------------------------------------------------------
// scan phase 3: add chunk offsets; rowptr[N_NODES] = N_EDGES
// ---------------------------------------------------------------------------
__global__ void lgcn_scan_p3(int* __restrict__ rowptr,
                             const int* __restrict__ blockSums) {
    int b    = blockIdx.x;
    int base = b * CHUNK;
    int t    = threadIdx.x;
    int off  = blockSums[b];
#pragma unroll
    for (int i = 0; i < 4; ++i) {
        int g = base + t * 4 + i;
        if (g < N_NODES) rowptr[g] += off;
    }
    if (b == 0 && t == 0) rowptr[N_NODES] = N_EDGES;
}

// ---------------------------------------------------------------------------
// XCD-private binned CSR build. Grid = NBIN * edgeChunks; block b handles
// edge chunk (b>>3) and position-bin (b&7). Dispatch round-robins XCDs by
// blockIdx%8, so each bin's csr lines are dirtied on exactly one XCD's L2
// and evict as FULL lines -> kills the ~17x scatter write amplification.
// The 8x redundant edge-stream reads are L2/L3-served.
// ---------------------------------------------------------------------------
__global__ void lgcn_csr_bin(const int*   __restrict__ src,
                             const int*   __restrict__ dst,
                             const float* __restrict__ vals,
                             const int*   __restrict__ rank,
                             const int*   __restrict__ rowptr,
                             uint2*       __restrict__ csr) {
    int b    = blockIdx.x;
    int bin  = b & (NBIN - 1);
    int e    = (b >> 3) * blockDim.x + threadIdx.x;
    if (e >= N_EDGES) return;
    int pos = rowptr[dst[e]] + rank[e];
    int lo  = bin * BINSZ;
    if (pos >= lo && pos < lo + BINSZ) {
        uint2 rec;
        rec.x = (unsigned)src[e];
        rec.y = __float_as_uint(vals[e]);
        csr[pos] = rec;
    }
}

// ---------------------------------------------------------------------------
// ego row lookup: concat(user,item,brand) without materializing the concat
// ---------------------------------------------------------------------------
__device__ __forceinline__ const float4* ego_row(const float* __restrict__ user,
                                                 const float* __restrict__ item,
                                                 const float* __restrict__ brand,
                                                 int r) {
    if (r < NUM_USERS)
        return reinterpret_cast<const float4*>(user) + (r << 4);
    else if (r < NUM_USERS + NUM_ITEMS)
        return reinterpret_cast<const float4*>(item) + ((r - NUM_USERS) << 4);
    else
        return reinterpret_cast<const float4*>(brand) + ((r - NUM_USERS - NUM_ITEMS) << 4);
}

// ---------------------------------------------------------------------------
// gather SpMM: 16 lanes per dst node (float4 each), 4 nodes per wave.
// 2-deep software pipeline. LAYER=1 reads ego arrays, writes h1.
// LAYER=2 reads h1, writes h2. LAYER=3 reads h2, fuses the full residual:
// out = (ego + h1 + h2 + sum) * 0.25.
// ---------------------------------------------------------------------------
template <int LAYER>
__global__ void lgcn_gather(const int*   __restrict__ rowptr,
                            const uint2* __restrict__ csr,
                            const float* __restrict__ user,
                            const float* __restrict__ item,
                            const float* __restrict__ brand,
                            const float* __restrict__ h1,
                            const float* __restrict__ h2,
                            float*       __restrict__ h_out,
                            float*       __restrict__ out) {
    int t    = blockIdx.x * blockDim.x + threadIdx.x;   // node*16 + q
    int node = t >> 4;
    int q    = t & 15;
    int beg = rowptr[node];
    int end = rowptr[node + 1];
    const float* h_src = (LAYER == 2) ? h1 : h2;        // LAYER 1 ignores this
    float4 sum = make_float4(0.f, 0.f, 0.f, 0.f);
    if (beg < end) {
        uint2 rec0 = csr[beg];
        uint2 rec1 = csr[(beg + 1 < end) ? beg + 1 : beg];
        const float4* p0 = (LAYER == 1)
            ? ego_row(user, item, brand, (int)rec0.x)
            : reinterpret_cast<const float4*>(h_src) + ((int)rec0.x << 4);
        float4 r0 = p0[q];
        for (int j = beg; j < end; ++j) {
            int jn = j + 2 < end ? j + 2 : end - 1;
            uint2 rec2 = csr[jn];                       // prefetch rec, 2 ahead
            const float4* p1 = (LAYER == 1)
                ? ego_row(user, item, brand, (int)rec1.x)
                : reinterpret_cast<const float4*>(h_src) + ((int)rec1.x << 4);
            float4 r1 = p1[q];
            float v = __uint_as_float(rec0.y);
            sum.x = fmaf(r0.x, v, sum.x);
            sum.y = fmaf(r0.y, v, sum.y);
            sum.z = fmaf(r0.z, v, sum.z);
            sum.w = fmaf(r0.w, v, sum.w);
            rec0 = rec1; rec1 = rec2; r0 = r1;
        }
    }
    if (LAYER != 3) {
        *reinterpret_cast<float4*>(h_out + t * 4) = sum;
    } else if (node < OUT_ROWS) {
        float4 eg = ego_row(user, item, brand, node)[q];
        float4 a1 = *(reinterpret_cast<const float4*>(h1) + (node << 4) + q);
        float4 a2 = *(reinterpret_cast<const float4*>(h2) + (node << 4) + q);
        float4 o;
        o.x = (eg.x + a1.x + a2.x + sum.x) * 0.25f;
        o.y = (eg.y + a1.y + a2.y + sum.y) * 0.25f;
        o.z = (eg.z + a1.z + a2.z + sum.z) * 0.25f;
        o.w = (eg.w + a1.w + a2.w + sum.w) * 0.25f;
        *reinterpret_cast<float4*>(out + t * 4) = o;
    }
}

extern "C" void kernel_launch(void* const* d_in, const int* in_sizes, int n_in,
                              void* d_out, int out_size, void* d_ws, size_t ws_size,
                              hipStream_t stream) {
    const float* user  = (const float*)d_in[0];
    const float* item  = (const float*)d_in[1];
    const float* brand = (const float*)d_in[2];
    const float* vals  = (const float*)d_in[3];
    const int*   src   = (const int*)d_in[4];
    const int*   dst   = (const int*)d_in[5];
    float* out = (float*)d_out;

    // workspace layout (32-bit words); keep csr 8B-aligned
    size_t W = 0;
    float* h1 = (float*)d_ws;                  W += (size_t)N_NODES * DIM;
    float* h2 = (float*)d_ws + W;              W += (size_t)N_NODES * DIM;
    uint2* csr = (uint2*)((float*)d_ws + W);   W += (size_t)N_EDGES * 2;
    int* rank      = (int*)((float*)d_ws + W); W += N_EDGES;
    int* rowptr    = (int*)((float*)d_ws + W); W += N_NODES + 2;
    int* counts    = (int*)((float*)d_ws + W); W += N_NODES;
    int* blockSums = (int*)((float*)d_ws + W); W += 512;
    (void)ws_size; (void)n_in; (void)in_sizes; (void)out_size;

    const int edgeBlocks   = (N_EDGES + 255) / 256;     // 4688
    const int gatherBlocks = (N_NODES * 16) / 256;      // 18750 (16 thr/node)

    // zero degree counters (poisoned workspace, and hist accumulates)
    hipMemsetAsync(counts, 0, (size_t)N_NODES * sizeof(int), stream);

    // build dst-sorted CSR: hist+rank -> scan -> XCD-binned record scatter
    lgcn_hist   <<<edgeBlocks, 256, 0, stream>>>(dst, counts, rank);
    lgcn_scan_p1<<<NB, 256, 0, stream>>>(counts, rowptr, blockSums);
    lgcn_scan_p2<<<1, 512, 0, stream>>>(blockSums);
    lgcn_scan_p3<<<NB, 256, 0, stream>>>(rowptr, blockSums);
    lgcn_csr_bin<<<NBIN * edgeBlocks, 256, 0, stream>>>(src, dst, vals, rank,
                                                        rowptr, csr);

    // 3 atomic-free SpMM layers; residual sum fused into layer 3
    lgcn_gather<1><<<gatherBlocks, 256, 0, stream>>>(rowptr, csr, user, item, brand,
                                                     h1, h2, h1, out);
    lgcn_gather<2><<<gatherBlocks, 256, 0, stream>>>(rowptr, csr, user, item, brand,
                                                     h1, h2, h2, out);
    lgcn_gather<3><<<gatherBlocks, 256, 0, stream>>>(rowptr, csr, user, item, brand,
                                                     h1, h2, nullptr, out);
}

// Round 6
// 272.416 us; speedup vs baseline: 1.4418x; 1.2124x over previous
//
#include <hip/hip_runtime.h>

#define NUM_USERS  150000
#define NUM_ITEMS  140000
#define NUM_BRANDS 10000
#define N_NODES    300000
#define DIM        64
#define N_EDGES    1200000
#define OUT_ROWS   290000          // users + items

#define CHUNK      1024            // elements per scan block
#define NB         ((N_NODES + CHUNK - 1) / CHUNK)   // 293 scan blocks

#define NBIN       8               // one bin per XCD
#define BINSZ      (N_EDGES / NBIN)                  // 150000 csr records

// ---------------------------------------------------------------------------
// bf16 helpers (h1/h2 stored as packed bf16: 64 dims = 16 uint2 per row)
// ---------------------------------------------------------------------------
__device__ __forceinline__ float bf_lo(unsigned u) { return __uint_as_float(u << 16); }
__device__ __forceinline__ float bf_hi(unsigned u) { return __uint_as_float(u & 0xffff0000u); }
__device__ __forceinline__ unsigned pack_bf(float a, float b) {
    unsigned ua = __float_as_uint(a); ua += 0x7fffu + ((ua >> 16) & 1u);
    unsigned ub = __float_as_uint(b); ub += 0x7fffu + ((ub >> 16) & 1u);
    return (ua >> 16) | (ub & 0xffff0000u);
}
__device__ __forceinline__ float4 unpack_bf4(uint2 w) {
    return make_float4(bf_lo(w.x), bf_hi(w.x), bf_lo(w.y), bf_hi(w.y));
}

// ---------------------------------------------------------------------------
// histogram of destination degrees + per-edge rank within its row
// ---------------------------------------------------------------------------
__global__ void lgcn_hist(const int* __restrict__ dst,
                          int* __restrict__ counts,
                          int* __restrict__ rank) {
    int e = blockIdx.x * blockDim.x + threadIdx.x;
    if (e >= N_EDGES) return;
    rank[e] = atomicAdd(&counts[dst[e]], 1);
}

// ---------------------------------------------------------------------------
// scan phase 1: per-1024-chunk exclusive scan (256 thr x 4 elem), chunk sums
// ---------------------------------------------------------------------------
__global__ void lgcn_scan_p1(const int* __restrict__ counts,
                             int* __restrict__ rowptr,
                             int* __restrict__ blockSums) {
    __shared__ int ts[256];
    int b    = blockIdx.x;
    int base = b * CHUNK;
    int t    = threadIdx.x;
    int c[4];
    int s = 0;
#pragma unroll
    for (int i = 0; i < 4; ++i) {
        int g = base + t * 4 + i;
        c[i] = (g < N_NODES) ? counts[g] : 0;
        s += c[i];
    }
    ts[t] = s;
    __syncthreads();
    for (int off = 1; off < 256; off <<= 1) {
        int v = (t >= off) ? ts[t - off] : 0;
        __syncthreads();
        ts[t] += v;
        __syncthreads();
    }
    int run = ts[t] - s;     // exclusive prefix of this thread's 4-group
#pragma unroll
    for (int i = 0; i < 4; ++i) {
        int g = base + t * 4 + i;
        if (g < N_NODES) rowptr[g] = run;
        run += c[i];
    }
    if (t == 255) blockSums[b] = ts[255];
}

// ---------------------------------------------------------------------------
// scan phase 2: single block exclusive-scans the NB (=293) chunk sums
// ---------------------------------------------------------------------------
__global__ void lgcn_scan_p2(int* __restrict__ blockSums) {
    __shared__ int sh[512];
    int t = threadIdx.x;
    int v = (t < NB) ? blockSums[t] : 0;
    sh[t] = v;
    __syncthreads();
    for (int off = 1; off < 512; off <<= 1) {
        int u = (t >= off) ? sh[t - off] : 0;
        __syncthreads();
        sh[t] += u;
        __syncthreads();
    }
    if (t < NB) blockSums[t] = sh[t] - v;   // exclusive
}

// ---------------------------------------------------------------------------
// scan phase 3: add chunk offsets; rowptr[N_NODES] = N_EDGES
// ---------------------------------------------------------------------------
__global__ void lgcn_scan_p3(int* __restrict__ rowptr,
                             const int* __restrict__ blockSums) {
    int b    = blockIdx.x;
    int base = b * CHUNK;
    int t    = threadIdx.x;
    int off  = blockSums[b];
#pragma unroll
    for (int i = 0; i < 4; ++i) {
        int g = base + t * 4 + i;
        if (g < N_NODES) rowptr[g] += off;
    }
    if (b == 0 && t == 0) rowptr[N_NODES] = N_EDGES;
}

// ---------------------------------------------------------------------------
// XCD-private binned CSR build (see R5 notes: kills scatter write-amp)
// ---------------------------------------------------------------------------
__global__ void lgcn_csr_bin(const int*   __restrict__ src,
                             const int*   __restrict__ dst,
                             const float* __restrict__ vals,
                             const int*   __restrict__ rank,
                             const int*   __restrict__ rowptr,
                             uint2*       __restrict__ csr) {
    int b    = blockIdx.x;
    int bin  = b & (NBIN - 1);
    int e    = (b >> 3) * blockDim.x + threadIdx.x;
    if (e >= N_EDGES) return;
    int pos = rowptr[dst[e]] + rank[e];
    int lo  = bin * BINSZ;
    if (pos >= lo && pos < lo + BINSZ) {
        uint2 rec;
        rec.x = (unsigned)src[e];
        rec.y = __float_as_uint(vals[e]);
        csr[pos] = rec;
    }
}

// ---------------------------------------------------------------------------
// ego row lookup: concat(user,item,brand) without materializing the concat
// ---------------------------------------------------------------------------
__device__ __forceinline__ const float4* ego_row(const float* __restrict__ user,
                                                 const float* __restrict__ item,
                                                 const float* __restrict__ brand,
                                                 int r) {
    if (r < NUM_USERS)
        return reinterpret_cast<const float4*>(user) + (r << 4);
    else if (r < NUM_USERS + NUM_ITEMS)
        return reinterpret_cast<const float4*>(item) + ((r - NUM_USERS) << 4);
    else
        return reinterpret_cast<const float4*>(brand) + ((r - NUM_USERS - NUM_ITEMS) << 4);
}

// row load: LAYER 1 reads fp32 ego (float4/lane); LAYER 2/3 read bf16 h rows
// (uint2 = 4 bf16 per lane, 128 B per row)
template <int LAYER>
__device__ __forceinline__ float4 load_row(const float* __restrict__ user,
                                           const float* __restrict__ item,
                                           const float* __restrict__ brand,
                                           const uint2* __restrict__ h_src,
                                           int r, int q) {
    if (LAYER == 1) return ego_row(user, item, brand, r)[q];
    return unpack_bf4(h_src[(r << 4) + q]);
}

// ---------------------------------------------------------------------------
// gather SpMM: 16 lanes per dst node, 4 nodes per wave, 2-deep pipeline.
// LAYER=1: ego(fp32) -> h1(bf16). LAYER=2: h1 -> h2. LAYER=3: h2 -> fused
// out = (ego + h1 + h2 + sum) * 0.25 (fp32).
// ---------------------------------------------------------------------------
template <int LAYER>
__global__ void lgcn_gather(const int*   __restrict__ rowptr,
                            const uint2* __restrict__ csr,
                            const float* __restrict__ user,
                            const float* __restrict__ item,
                            const float* __restrict__ brand,
                            const uint2* __restrict__ h1,
                            const uint2* __restrict__ h2,
                            uint2*       __restrict__ h_out,
                            float*       __restrict__ out) {
    int t    = blockIdx.x * blockDim.x + threadIdx.x;   // node*16 + q
    int node = t >> 4;
    int q    = t & 15;
    int beg = rowptr[node];
    int end = rowptr[node + 1];
    const uint2* h_src = (LAYER == 2) ? h1 : h2;        // LAYER 1 ignores this
    float4 sum = make_float4(0.f, 0.f, 0.f, 0.f);
    if (beg < end) {
        uint2 rec0 = csr[beg];
        uint2 rec1 = csr[(beg + 1 < end) ? beg + 1 : beg];
        float4 r0 = load_row<LAYER>(user, item, brand, h_src, (int)rec0.x, q);
        for (int j = beg; j < end; ++j) {
            int jn = j + 2 < end ? j + 2 : end - 1;
            uint2 rec2 = csr[jn];                       // prefetch rec, 2 ahead
            float4 r1 = load_row<LAYER>(user, item, brand, h_src, (int)rec1.x, q);
            float v = __uint_as_float(rec0.y);
            sum.x = fmaf(r0.x, v, sum.x);
            sum.y = fmaf(r0.y, v, sum.y);
            sum.z = fmaf(r0.z, v, sum.z);
            sum.w = fmaf(r0.w, v, sum.w);
            rec0 = rec1; rec1 = rec2; r0 = r1;
        }
    }
    if (LAYER != 3) {
        h_out[t] = make_uint2(pack_bf(sum.x, sum.y), pack_bf(sum.z, sum.w));
    } else if (node < OUT_ROWS) {
        float4 eg = ego_row(user, item, brand, node)[q];
        float4 a1 = unpack_bf4(h1[(node << 4) + q]);
        float4 a2 = unpack_bf4(h2[(node << 4) + q]);
        float4 o;
        o.x = (eg.x + a1.x + a2.x + sum.x) * 0.25f;
        o.y = (eg.y + a1.y + a2.y + sum.y) * 0.25f;
        o.z = (eg.z + a1.z + a2.z + sum.z) * 0.25f;
        o.w = (eg.w + a1.w + a2.w + sum.w) * 0.25f;
        *reinterpret_cast<float4*>(out + t * 4) = o;
    }
}

extern "C" void kernel_launch(void* const* d_in, const int* in_sizes, int n_in,
                              void* d_out, int out_size, void* d_ws, size_t ws_size,
                              hipStream_t stream) {
    const float* user  = (const float*)d_in[0];
    const float* item  = (const float*)d_in[1];
    const float* brand = (const float*)d_in[2];
    const float* vals  = (const float*)d_in[3];
    const int*   src   = (const int*)d_in[4];
    const int*   dst   = (const int*)d_in[5];
    float* out = (float*)d_out;

    // workspace layout (32-bit words); 8B alignment for uint2 arrays
    size_t W = 0;
    uint2* h1  = (uint2*)d_ws;                 W += (size_t)N_NODES * 16 * 2;  // bf16 rows
    uint2* h2  = (uint2*)((int*)d_ws + W);     W += (size_t)N_NODES * 16 * 2;
    uint2* csr = (uint2*)((int*)d_ws + W);     W += (size_t)N_EDGES * 2;
    int* rank      = (int*)d_ws + W;           W += N_EDGES;
    int* rowptr    = (int*)d_ws + W;           W += N_NODES + 2;
    int* counts    = (int*)d_ws + W;           W += N_NODES;
    int* blockSums = (int*)d_ws + W;           W += 512;
    (void)ws_size; (void)n_in; (void)in_sizes; (void)out_size;

    const int edgeBlocks   = (N_EDGES + 255) / 256;     // 4688
    const int gatherBlocks = (N_NODES * 16) / 256;      // 18750 (16 thr/node)

    // zero degree counters (poisoned workspace, and hist accumulates)
    hipMemsetAsync(counts, 0, (size_t)N_NODES * sizeof(int), stream);

    // build dst-sorted CSR: hist+rank -> scan -> XCD-binned record scatter
    lgcn_hist   <<<edgeBlocks, 256, 0, stream>>>(dst, counts, rank);
    lgcn_scan_p1<<<NB, 256, 0, stream>>>(counts, rowptr, blockSums);
    lgcn_scan_p2<<<1, 512, 0, stream>>>(blockSums);
    lgcn_scan_p3<<<NB, 256, 0, stream>>>(rowptr, blockSums);
    lgcn_csr_bin<<<NBIN * edgeBlocks, 256, 0, stream>>>(src, dst, vals, rank,
                                                        rowptr, csr);

    // 3 atomic-free SpMM layers (bf16 intermediates); residual fused in L3
    lgcn_gather<1><<<gatherBlocks, 256, 0, stream>>>(rowptr, csr, user, item, brand,
                                                     h1, h2, h1, out);
    lgcn_gather<2><<<gatherBlocks, 256, 0, stream>>>(rowptr, csr, user, item, brand,
                                                     h1, h2, h2, out);
    lgcn_gather<3><<<gatherBlocks, 256, 0, stream>>>(rowptr, csr, user, item, brand,
                                                     h1, h2, nullptr, out);
}

// Round 7
// 261.426 us; speedup vs baseline: 1.5024x; 1.0420x over previous
//
#include <hip/hip_runtime.h>

#define NUM_USERS  150000
#define NUM_ITEMS  140000
#define NUM_BRANDS 10000
#define N_NODES    300000
#define DIM        64
#define N_EDGES    1200000
#define OUT_ROWS   290000          // users + items

#define CHUNK      1024            // elements per scan block
#define NB         ((N_NODES + CHUNK - 1) / CHUNK)   // 293 scan blocks

#define NBIN       8               // one bin per XCD
#define BINSZ      (N_EDGES / NBIN)                  // 150000 csr records

// ---------------------------------------------------------------------------
// bf16 helpers (h1/h2 stored as packed bf16: 64 dims = 8 uint4 per row)
// ---------------------------------------------------------------------------
__device__ __forceinline__ float bf_lo(unsigned u) { return __uint_as_float(u << 16); }
__device__ __forceinline__ float bf_hi(unsigned u) { return __uint_as_float(u & 0xffff0000u); }
__device__ __forceinline__ unsigned pack_bf(float a, float b) {
    unsigned ua = __float_as_uint(a); ua += 0x7fffu + ((ua >> 16) & 1u);
    unsigned ub = __float_as_uint(b); ub += 0x7fffu + ((ub >> 16) & 1u);
    return (ua >> 16) | (ub & 0xffff0000u);
}

// ---------------------------------------------------------------------------
// histogram of destination degrees + per-edge rank within its row
// ---------------------------------------------------------------------------
__global__ void lgcn_hist(const int* __restrict__ dst,
                          int* __restrict__ counts,
                          int* __restrict__ rank) {
    int e = blockIdx.x * blockDim.x + threadIdx.x;
    if (e >= N_EDGES) return;
    rank[e] = atomicAdd(&counts[dst[e]], 1);
}

// ---------------------------------------------------------------------------
// scan phase 1: per-1024-chunk exclusive scan (256 thr x 4 elem), chunk sums
// ---------------------------------------------------------------------------
__global__ void lgcn_scan_p1(const int* __restrict__ counts,
                             int* __restrict__ rowptr,
                             int* __restrict__ blockSums) {
    __shared__ int ts[256];
    int b    = blockIdx.x;
    int base = b * CHUNK;
    int t    = threadIdx.x;
    int c[4];
    int s = 0;
#pragma unroll
    for (int i = 0; i < 4; ++i) {
        int g = base + t * 4 + i;
        c[i] = (g < N_NODES) ? counts[g] : 0;
        s += c[i];
    }
    ts[t] = s;
    __syncthreads();
    for (int off = 1; off < 256; off <<= 1) {
        int v = (t >= off) ? ts[t - off] : 0;
        __syncthreads();
        ts[t] += v;
        __syncthreads();
    }
    int run = ts[t] - s;     // exclusive prefix of this thread's 4-group
#pragma unroll
    for (int i = 0; i < 4; ++i) {
        int g = base + t * 4 + i;
        if (g < N_NODES) rowptr[g] = run;
        run += c[i];
    }
    if (t == 255) blockSums[b] = ts[255];
}

// ---------------------------------------------------------------------------
// scan phase 2: single block exclusive-scans the NB (=293) chunk sums
// ---------------------------------------------------------------------------
__global__ void lgcn_scan_p2(int* __restrict__ blockSums) {
    __shared__ int sh[512];
    int t = threadIdx.x;
    int v = (t < NB) ? blockSums[t] : 0;
    sh[t] = v;
    __syncthreads();
    for (int off = 1; off < 512; off <<= 1) {
        int u = (t >= off) ? sh[t - off] : 0;
        __syncthreads();
        sh[t] += u;
        __syncthreads();
    }
    if (t < NB) blockSums[t] = sh[t] - v;   // exclusive
}

// ---------------------------------------------------------------------------
// scan phase 3: add chunk offsets; rowptr[N_NODES] = N_EDGES
// ---------------------------------------------------------------------------
__global__ void lgcn_scan_p3(int* __restrict__ rowptr,
                             const int* __restrict__ blockSums) {
    int b    = blockIdx.x;
    int base = b * CHUNK;
    int t    = threadIdx.x;
    int off  = blockSums[b];
#pragma unroll
    for (int i = 0; i < 4; ++i) {
        int g = base + t * 4 + i;
        if (g < N_NODES) rowptr[g] += off;
    }
    if (b == 0 && t == 0) rowptr[N_NODES] = N_EDGES;
}

// ---------------------------------------------------------------------------
// XCD-private binned CSR build (see R5 notes: kills scatter write-amp)
// ---------------------------------------------------------------------------
__global__ void lgcn_csr_bin(const int*   __restrict__ src,
                             const int*   __restrict__ dst,
                             const float* __restrict__ vals,
                             const int*   __restrict__ rank,
                             const int*   __restrict__ rowptr,
                             uint2*       __restrict__ csr) {
    int b    = blockIdx.x;
    int bin  = b & (NBIN - 1);
    int e    = (b >> 3) * blockDim.x + threadIdx.x;
    if (e >= N_EDGES) return;
    int pos = rowptr[dst[e]] + rank[e];
    int lo  = bin * BINSZ;
    if (pos >= lo && pos < lo + BINSZ) {
        uint2 rec;
        rec.x = (unsigned)src[e];
        rec.y = __float_as_uint(vals[e]);
        csr[pos] = rec;
    }
}

// ---------------------------------------------------------------------------
// ego row lookup: concat(user,item,brand) without materializing the concat
// ---------------------------------------------------------------------------
__device__ __forceinline__ const float4* ego_row(const float* __restrict__ user,
                                                 const float* __restrict__ item,
                                                 const float* __restrict__ brand,
                                                 int r) {
    if (r < NUM_USERS)
        return reinterpret_cast<const float4*>(user) + (r << 4);
    else if (r < NUM_USERS + NUM_ITEMS)
        return reinterpret_cast<const float4*>(item) + ((r - NUM_USERS) << 4);
    else
        return reinterpret_cast<const float4*>(brand) + ((r - NUM_USERS - NUM_ITEMS) << 4);
}

// row load, 8 floats per lane (8 lanes per row).
// LAYER 1: fp32 ego row (2x float4). LAYER 2/3: bf16 h row (1x uint4).
template <int LAYER>
__device__ __forceinline__ void load8(const float* __restrict__ user,
                                      const float* __restrict__ item,
                                      const float* __restrict__ brand,
                                      const uint4* __restrict__ h_src,
                                      int r, int q, float4& a, float4& b) {
    if (LAYER == 1) {
        const float4* er = ego_row(user, item, brand, r);
        a = er[2 * q];
        b = er[2 * q + 1];
    } else {
        uint4 w = h_src[(r << 3) + q];
        a = make_float4(bf_lo(w.x), bf_hi(w.x), bf_lo(w.y), bf_hi(w.y));
        b = make_float4(bf_lo(w.z), bf_hi(w.z), bf_lo(w.w), bf_hi(w.w));
    }
}

// ---------------------------------------------------------------------------
// gather SpMM: 8 lanes per dst node (8 dims/lane), 8 nodes per wave ->
// ~2x the outstanding row loads per wave vs the 16-lane version.
// 2-deep software pipeline. LAYER=1: ego(fp32)->h1(bf16). LAYER=2: h1->h2.
// LAYER=3: h2 -> fused out = (ego + h1 + h2 + sum) * 0.25 (fp32).
// ---------------------------------------------------------------------------
template <int LAYER>
__global__ void lgcn_gather(const int*   __restrict__ rowptr,
                            const uint2* __restrict__ csr,
                            const float* __restrict__ user,
                            const float* __restrict__ item,
                            const float* __restrict__ brand,
                            const uint4* __restrict__ h1,
                            const uint4* __restrict__ h2,
                            uint4*       __restrict__ h_out,
                            float*       __restrict__ out) {
    int t    = blockIdx.x * blockDim.x + threadIdx.x;   // node*8 + q
    int node = t >> 3;
    int q    = t & 7;
    int beg = rowptr[node];
    int end = rowptr[node + 1];
    const uint4* h_src = (LAYER == 2) ? h1 : h2;        // LAYER 1 ignores this
    float4 s0 = make_float4(0.f, 0.f, 0.f, 0.f);
    float4 s1 = make_float4(0.f, 0.f, 0.f, 0.f);
    if (beg < end) {
        uint2 rec0 = csr[beg];
        uint2 rec1 = csr[(beg + 1 < end) ? beg + 1 : beg];
        float4 a0, b0;
        load8<LAYER>(user, item, brand, h_src, (int)rec0.x, q, a0, b0);
        for (int j = beg; j < end; ++j) {
            int jn = j + 2 < end ? j + 2 : end - 1;
            uint2 rec2 = csr[jn];                       // prefetch rec, 2 ahead
            float4 a1, b1;
            load8<LAYER>(user, item, brand, h_src, (int)rec1.x, q, a1, b1);
            float v = __uint_as_float(rec0.y);
            s0.x = fmaf(a0.x, v, s0.x);
            s0.y = fmaf(a0.y, v, s0.y);
            s0.z = fmaf(a0.z, v, s0.z);
            s0.w = fmaf(a0.w, v, s0.w);
            s1.x = fmaf(b0.x, v, s1.x);
            s1.y = fmaf(b0.y, v, s1.y);
            s1.z = fmaf(b0.z, v, s1.z);
            s1.w = fmaf(b0.w, v, s1.w);
            rec0 = rec1; rec1 = rec2; a0 = a1; b0 = b1;
        }
    }
    if (LAYER != 3) {
        uint4 w;
        w.x = pack_bf(s0.x, s0.y);
        w.y = pack_bf(s0.z, s0.w);
        w.z = pack_bf(s1.x, s1.y);
        w.w = pack_bf(s1.z, s1.w);
        h_out[t] = w;
    } else if (node < OUT_ROWS) {
        const float4* er = ego_row(user, item, brand, node);
        float4 e0 = er[2 * q];
        float4 e1 = er[2 * q + 1];
        uint4 w1 = h1[t];
        uint4 w2 = h2[t];
        float4 o0, o1;
        o0.x = (e0.x + bf_lo(w1.x) + bf_lo(w2.x) + s0.x) * 0.25f;
        o0.y = (e0.y + bf_hi(w1.x) + bf_hi(w2.x) + s0.y) * 0.25f;
        o0.z = (e0.z + bf_lo(w1.y) + bf_lo(w2.y) + s0.z) * 0.25f;
        o0.w = (e0.w + bf_hi(w1.y) + bf_hi(w2.y) + s0.w) * 0.25f;
        o1.x = (e1.x + bf_lo(w1.z) + bf_lo(w2.z) + s1.x) * 0.25f;
        o1.y = (e1.y + bf_hi(w1.z) + bf_hi(w2.z) + s1.y) * 0.25f;
        o1.z = (e1.z + bf_lo(w1.w) + bf_lo(w2.w) + s1.z) * 0.25f;
        o1.w = (e1.w + bf_hi(w1.w) + bf_hi(w2.w) + s1.w) * 0.25f;
        float4* o = reinterpret_cast<float4*>(out) + t * 2;
        o[0] = o0;
        o[1] = o1;
    }
}

extern "C" void kernel_launch(void* const* d_in, const int* in_sizes, int n_in,
                              void* d_out, int out_size, void* d_ws, size_t ws_size,
                              hipStream_t stream) {
    const float* user  = (const float*)d_in[0];
    const float* item  = (const float*)d_in[1];
    const float* brand = (const float*)d_in[2];
    const float* vals  = (const float*)d_in[3];
    const int*   src   = (const int*)d_in[4];
    const int*   dst   = (const int*)d_in[5];
    float* out = (float*)d_out;

    // workspace layout (32-bit words); 16B alignment for uint4 arrays
    size_t W = 0;
    uint4* h1  = (uint4*)d_ws;                 W += (size_t)N_NODES * 32;   // bf16 rows (128B)
    uint4* h2  = (uint4*)((int*)d_ws + W);     W += (size_t)N_NODES * 32;
    uint2* csr = (uint2*)((int*)d_ws + W);     W += (size_t)N_EDGES * 2;
    int* rank      = (int*)d_ws + W;           W += N_EDGES;
    int* rowptr    = (int*)d_ws + W;           W += N_NODES + 2;
    int* counts    = (int*)d_ws + W;           W += N_NODES;
    int* blockSums = (int*)d_ws + W;           W += 512;
    (void)ws_size; (void)n_in; (void)in_sizes; (void)out_size;

    const int edgeBlocks   = (N_EDGES + 255) / 256;     // 4688
    const int gatherBlocks = (N_NODES * 8) / 256;       // 9375 (8 thr/node)

    // zero degree counters (poisoned workspace, and hist accumulates)
    hipMemsetAsync(counts, 0, (size_t)N_NODES * sizeof(int), stream);

    // build dst-sorted CSR: hist+rank -> scan -> XCD-binned record scatter
    lgcn_hist   <<<edgeBlocks, 256, 0, stream>>>(dst, counts, rank);
    lgcn_scan_p1<<<NB, 256, 0, stream>>>(counts, rowptr, blockSums);
    lgcn_scan_p2<<<1, 512, 0, stream>>>(blockSums);
    lgcn_scan_p3<<<NB, 256, 0, stream>>>(rowptr, blockSums);
    lgcn_csr_bin<<<NBIN * edgeBlocks, 256, 0, stream>>>(src, dst, vals, rank,
                                                        rowptr, csr);

    // 3 atomic-free SpMM layers (bf16 intermediates); residual fused in L3
    lgcn_gather<1><<<gatherBlocks, 256, 0, stream>>>(rowptr, csr, user, item, brand,
                                                     h1, h2, h1, out);
    lgcn_gather<2><<<gatherBlocks, 256, 0, stream>>>(rowptr, csr, user, item, brand,
                                                     h1, h2, h2, out);
    lgcn_gather<3><<<gatherBlocks, 256, 0, stream>>>(rowptr, csr, user, item, brand,
                                                     h1, h2, nullptr, out);
}